// Round 1
// baseline (377.061 us; speedup 1.0000x reference)
//
#include <hip/hip_runtime.h>
#include <stdint.h>

#define M_DIM 8192
#define K_DIM 4096
#define N_DIM 4096

typedef unsigned short u16;
typedef __bf16 bf16x8 __attribute__((ext_vector_type(8)));
typedef float f32x4 __attribute__((ext_vector_type(4)));
typedef float float4v __attribute__((ext_vector_type(4)));
typedef u16 u16x4 __attribute__((ext_vector_type(4)));

// sign(v) encoded as bf16 bit pattern: +1 -> 0x3F80, -1 -> 0xBF80, 0 -> 0
__device__ __forceinline__ u16 sign_bits(float v) {
  return v > 0.0f ? (u16)0x3F80 : (v < 0.0f ? (u16)0xBF80 : (u16)0);
}

// ---------------- binarize X: [M][K] f32 -> [M][K] bf16(sign) ----------------
__global__ void binarize_x_kernel(const float* __restrict__ in, u16* __restrict__ out, int n4) {
  int i = blockIdx.x * blockDim.x + threadIdx.x;
  int stride = gridDim.x * blockDim.x;
  for (; i < n4; i += stride) {
    float4v v = ((const float4v*)in)[i];
    u16x4 o;
    o.x = sign_bits(v.x);
    o.y = sign_bits(v.y);
    o.z = sign_bits(v.z);
    o.w = sign_bits(v.w);
    ((u16x4*)out)[i] = o;
  }
}

// ------- binarize + transpose W: [K][N] f32 -> [N][K] bf16(sign) -------------
// 64x64 tiles through LDS, coalesced read and write.
__global__ void binT_w_kernel(const float* __restrict__ w, u16* __restrict__ wT) {
  __shared__ u16 tile[64][65];  // +1 pad to break bank conflicts
  const int bn = blockIdx.x * 64;  // n block
  const int bk = blockIdx.y * 64;  // k block
  const int tid = threadIdx.x;     // 256 threads

#pragma unroll
  for (int it = 0; it < 4; ++it) {
    int idx = tid + it * 256;     // 0..1023
    int r = idx >> 4;             // k-local 0..63
    int c = (idx & 15) * 4;       // n-local 0..60
    float4v v = *(const float4v*)&w[(size_t)(bk + r) * N_DIM + bn + c];
    tile[c + 0][r] = sign_bits(v.x);
    tile[c + 1][r] = sign_bits(v.y);
    tile[c + 2][r] = sign_bits(v.z);
    tile[c + 3][r] = sign_bits(v.w);
  }
  __syncthreads();
#pragma unroll
  for (int it = 0; it < 4; ++it) {
    int idx = tid + it * 256;
    int rn = idx >> 4;            // n-local
    int ck = (idx & 15) * 4;      // k-local
    u16x4 o;
    o.x = tile[rn][ck + 0];
    o.y = tile[rn][ck + 1];
    o.z = tile[rn][ck + 2];
    o.w = tile[rn][ck + 3];
    *(u16x4*)&wT[(size_t)(bn + rn) * K_DIM + bk + ck] = o;
  }
}

// ---------------- GEMM: C[M][N] = Abin[M][K] * BtBin[N][K]^T -----------------
// m97 structure: 128x128 tile, BK=64, 4 waves (2x2), 4x4 16x16x32 MFMA frags
// per wave, global_load_lds width=16 staging, 2 barriers per K-step.
#define BM 128
#define BN 128
#define BK 64

__device__ __forceinline__ void gload_lds16(const void* g, void* l) {
  __builtin_amdgcn_global_load_lds(
      (const __attribute__((address_space(1))) void*)g,
      (__attribute__((address_space(3))) void*)l, 16, 0, 0);
}

__global__ __launch_bounds__(256) void gemm_bin_kernel(const u16* __restrict__ A,
                                                       const u16* __restrict__ Bt,
                                                       float* __restrict__ C) {
  __shared__ u16 As[BM * BK];  // 16 KB
  __shared__ u16 Bs[BN * BK];  // 16 KB

  const int tid = threadIdx.x;
  const int lane = tid & 63;
  const int wid = tid >> 6;
  const int wr = wid >> 1;  // 0..1
  const int wc = wid & 1;   // 0..1

  // XCD-aware bijective swizzle: nwg = 64*32 = 2048, divisible by 8.
  const int nwg = gridDim.x;
  const int per = nwg >> 3;
  const int b = blockIdx.x;
  const int sw = (b & 7) * per + (b >> 3);
  const int tiles_n = N_DIM / BN;  // 32
  const int bm = (sw / tiles_n) * BM;
  const int bn = (sw % tiles_n) * BN;

  const size_t abase = (size_t)bm * K_DIM;
  const size_t bbase = (size_t)bn * K_DIM;

  f32x4 acc[4][4] = {};

  for (int kt = 0; kt < K_DIM; kt += BK) {
    // ---- stage A and B tiles (each wave: 4 chunks of 8 rows x 64 cols) ----
#pragma unroll
    for (int i = wid; i < 16; i += 4) {
      const u16* ga = A + abase + (size_t)(i * 8 + (lane >> 3)) * K_DIM + kt + (lane & 7) * 8;
      gload_lds16(ga, &As[i * 512]);  // LDS base uniform per wave; HW adds lane*16B
      const u16* gb = Bt + bbase + (size_t)(i * 8 + (lane >> 3)) * K_DIM + kt + (lane & 7) * 8;
      gload_lds16(gb, &Bs[i * 512]);
    }
    __syncthreads();

    // ---- compute: 2 k-chunks of 32, 4x4 fragments ----
#pragma unroll
    for (int kk = 0; kk < 2; ++kk) {
      bf16x8 af[4], bfr[4];
#pragma unroll
      for (int m = 0; m < 4; ++m)
        af[m] = *(const bf16x8*)&As[(wr * 64 + m * 16 + (lane & 15)) * BK + kk * 32 + (lane >> 4) * 8];
#pragma unroll
      for (int n = 0; n < 4; ++n)
        bfr[n] = *(const bf16x8*)&Bs[(wc * 64 + n * 16 + (lane & 15)) * BK + kk * 32 + (lane >> 4) * 8];
#pragma unroll
      for (int m = 0; m < 4; ++m)
#pragma unroll
        for (int n = 0; n < 4; ++n)
          acc[m][n] = __builtin_amdgcn_mfma_f32_16x16x32_bf16(af[m], bfr[n], acc[m][n], 0, 0, 0);
    }
    __syncthreads();
  }

  // ---- epilogue: C/D layout col = lane&15, row = (lane>>4)*4 + reg ----
  const int crow0 = bm + wr * 64;
  const int ccol0 = bn + wc * 64;
#pragma unroll
  for (int m = 0; m < 4; ++m)
#pragma unroll
    for (int n = 0; n < 4; ++n)
#pragma unroll
      for (int j = 0; j < 4; ++j)
        C[(size_t)(crow0 + m * 16 + (lane >> 4) * 4 + j) * N_DIM + ccol0 + n * 16 + (lane & 15)] =
            acc[m][n][j];
}

// -------- naive fallback (only if workspace is too small) --------
__global__ void naive_bin_gemm(const float* __restrict__ X, const float* __restrict__ W,
                               float* __restrict__ C) {
  int j = blockIdx.x * blockDim.x + threadIdx.x;  // over N
  int i = blockIdx.y;                             // over M
  if (j >= N_DIM) return;
  float s = 0.0f;
  for (int k = 0; k < K_DIM; ++k) {
    float xv = X[(size_t)i * K_DIM + k];
    float wv = W[(size_t)k * N_DIM + j];
    float sx = (float)((xv > 0.0f) - (xv < 0.0f));
    float sw = (float)((wv > 0.0f) - (wv < 0.0f));
    s += sx * sw;
  }
  C[(size_t)i * N_DIM + j] = s;
}

extern "C" void kernel_launch(void* const* d_in, const int* in_sizes, int n_in,
                              void* d_out, int out_size, void* d_ws, size_t ws_size,
                              hipStream_t stream) {
  const float* x = (const float*)d_in[0];  // [M][K]
  const float* w = (const float*)d_in[1];  // [K][N]
  float* out = (float*)d_out;              // [M][N]

  const size_t xb_bytes = (size_t)M_DIM * K_DIM * sizeof(u16);  // 67 MB
  const size_t wt_bytes = (size_t)K_DIM * N_DIM * sizeof(u16);  // 33.5 MB

  if (ws_size >= xb_bytes + wt_bytes) {
    u16* xb = (u16*)d_ws;
    u16* wt = (u16*)((char*)d_ws + xb_bytes);

    binarize_x_kernel<<<2048, 256, 0, stream>>>(x, xb, M_DIM * K_DIM / 4);
    binT_w_kernel<<<dim3(N_DIM / 64, K_DIM / 64), dim3(256), 0, stream>>>(w, wt);

    const int grid = (M_DIM / BM) * (N_DIM / BN);  // 64 * 32 = 2048
    gemm_bin_kernel<<<grid, 256, 0, stream>>>(xb, wt, out);
  } else {
    naive_bin_gemm<<<dim3(N_DIM / 256, M_DIM), dim3(256), 0, stream>>>(x, w, out);
  }
}

// Round 2
// 269.769 us; speedup vs baseline: 1.3977x; 1.3977x over previous
//
#include <hip/hip_runtime.h>
#include <stdint.h>

#define M_DIM 8192
#define K_DIM 4096
#define N_DIM 4096

typedef unsigned short u16;
typedef __bf16 bf16x8 __attribute__((ext_vector_type(8)));
typedef float f32x4 __attribute__((ext_vector_type(4)));
typedef float float4v __attribute__((ext_vector_type(4)));
typedef u16 u16x4 __attribute__((ext_vector_type(4)));

// sign(v) encoded as bf16 bit pattern: +1 -> 0x3F80, -1 -> 0xBF80, 0 -> 0
__device__ __forceinline__ u16 sign_bits(float v) {
  return v > 0.0f ? (u16)0x3F80 : (v < 0.0f ? (u16)0xBF80 : (u16)0);
}

// ---------------- binarize X: [M][K] f32 -> [M][K] bf16(sign) ----------------
__global__ void binarize_x_kernel(const float* __restrict__ in, u16* __restrict__ out, int n4) {
  int i = blockIdx.x * blockDim.x + threadIdx.x;
  int stride = gridDim.x * blockDim.x;
  for (; i < n4; i += stride) {
    float4v v = ((const float4v*)in)[i];
    u16x4 o;
    o.x = sign_bits(v.x);
    o.y = sign_bits(v.y);
    o.z = sign_bits(v.z);
    o.w = sign_bits(v.w);
    ((u16x4*)out)[i] = o;
  }
}

// ------- binarize + transpose W: [K][N] f32 -> [N][K] bf16(sign) -------------
__global__ void binT_w_kernel(const float* __restrict__ w, u16* __restrict__ wT) {
  __shared__ u16 tile[64][65];
  const int bn = blockIdx.x * 64;
  const int bk = blockIdx.y * 64;
  const int tid = threadIdx.x;

#pragma unroll
  for (int it = 0; it < 4; ++it) {
    int idx = tid + it * 256;
    int r = idx >> 4;
    int c = (idx & 15) * 4;
    float4v v = *(const float4v*)&w[(size_t)(bk + r) * N_DIM + bn + c];
    tile[c + 0][r] = sign_bits(v.x);
    tile[c + 1][r] = sign_bits(v.y);
    tile[c + 2][r] = sign_bits(v.z);
    tile[c + 3][r] = sign_bits(v.w);
  }
  __syncthreads();
#pragma unroll
  for (int it = 0; it < 4; ++it) {
    int idx = tid + it * 256;
    int rn = idx >> 4;
    int ck = (idx & 15) * 4;
    u16x4 o;
    o.x = tile[rn][ck + 0];
    o.y = tile[rn][ck + 1];
    o.z = tile[rn][ck + 2];
    o.w = tile[rn][ck + 3];
    *(u16x4*)&wT[(size_t)(bn + rn) * K_DIM + bk + ck] = o;
  }
}

// ------------------------------------------------------------------
// 8-phase 256x256 GEMM: C[M][N] = A[M][K] * Bt[N][K]^T, bf16 in, f32 out.
// 8 waves (2M x 4N), BK=64, 2 K-tiles double-buffered, 4 phases/K-tile.
// T2 st-swizzle (col_bytes ^= (row&7)<<4) via pre-swizzled global source,
// counted vmcnt(4) once per K-tile, setprio around MFMA clusters.
// ------------------------------------------------------------------
#define BM 256
#define BN 256
#define BK 64
#define NT (K_DIM / BK)

__device__ __forceinline__ void gload_lds16(const u16* g, u16* l) {
  __builtin_amdgcn_global_load_lds(
      (const __attribute__((address_space(1))) void*)g,
      (__attribute__((address_space(3))) void*)l, 16, 0, 0);
}

__global__ __launch_bounds__(512, 2) void gemm_bin_8ph(const u16* __restrict__ A,
                                                       const u16* __restrict__ Bt,
                                                       float* __restrict__ C) {
  // slots per buffer: 0 = A rows[0,128), 1 = A rows[128,256),
  //                   2 = Bt rows[0,128), 3 = Bt rows[128,256). 128 KiB total.
  __shared__ u16 lds[2][4][128 * 64];

  const int tid = threadIdx.x;
  const int lane = tid & 63;
  const int wid = tid >> 6;  // 0..7
  const int wr = wid >> 2;   // 0..1 (M half)
  const int wc = wid & 3;    // 0..3 (N quarter)

  // XCD-aware swizzle, nwg = 512 (divisible by 8 -> bijective)
  const int b = blockIdx.x;
  const int sw = (b & 7) * (gridDim.x >> 3) + (b >> 3);
  const int tiles_n = N_DIM / BN;  // 16
  const int bm = (sw / tiles_n) * BM;
  const int bn = (sw % tiles_n) * BN;

  const int l15 = lane & 15;
  const int g4 = lane >> 4;
  const int srow = lane >> 3;                                // 0..7
  const int swz8 = (((lane & 7) ^ ((lane >> 3) & 7)) << 3);  // pre-swizzled col (elems)

  // stage one 128x64 half-tile (2 x global_load_lds per wave, linear LDS dest,
  // swizzled global source so reads can XOR-deswizzle).
  auto stage = [&](int buf, int slot, const u16* gbase) {
#pragma unroll
    for (int i = 0; i < 2; ++i) {
      const u16* g = gbase + (size_t)(i * 64 + wid * 8 + srow) * K_DIM + swz8;
      gload_lds16(g, &lds[buf][slot][(i * 64 + wid * 8) * 64]);
    }
  };

  f32x4 acc[8][4] = {};

  // ---- prologue: tile0 fully + B-halves of tile1 (6 half-tiles, 12 loads) ----
  {
    const u16* Abase = A + (size_t)bm * K_DIM;
    const u16* Bbase = Bt + (size_t)bn * K_DIM;
    stage(0, 0, Abase);
    stage(0, 1, Abase + (size_t)128 * K_DIM);
    stage(0, 2, Bbase);
    stage(0, 3, Bbase + (size_t)128 * K_DIM);
    stage(1, 2, Bbase + BK);
    stage(1, 3, Bbase + (size_t)128 * K_DIM + BK);
  }
  asm volatile("s_waitcnt vmcnt(4)" ::: "memory");  // drain tile0, B(1) in flight
  __builtin_amdgcn_s_barrier();

  bf16x8 a[4][2], b01[2][2], b23[2][2];

  for (int t = 0; t < NT; ++t) {
    const int buf = t & 1;
    const int kt = t * BK;
    const u16* As = &lds[buf][wr][0];
    const u16* Bs = &lds[buf][2 + (wc >> 1)][0];
    const int brow0 = (wc & 1) * 64;
    const u16* Anext = A + (size_t)bm * K_DIM + kt + BK;        // tile t+1
    const u16* Bnext2 = Bt + (size_t)bn * K_DIM + kt + 2 * BK;  // tile t+2

    // ===== phase 1: read a(mh0) + b01 ; stage A0(t+1) ; MFMA Q(mh0,n01) =====
#pragma unroll
    for (int m = 0; m < 4; ++m)
#pragma unroll
      for (int kk = 0; kk < 2; ++kk) {
        int row = m * 16 + l15;
        int col = (kk * 32 + g4 * 8) ^ ((row & 7) << 3);
        a[m][kk] = *(const bf16x8*)&As[row * 64 + col];
      }
#pragma unroll
    for (int n = 0; n < 2; ++n)
#pragma unroll
      for (int kk = 0; kk < 2; ++kk) {
        int row = brow0 + n * 16 + l15;
        int col = (kk * 32 + g4 * 8) ^ ((row & 7) << 3);
        b01[n][kk] = *(const bf16x8*)&Bs[row * 64 + col];
      }
    if (t + 1 < NT) stage(buf ^ 1, 0, Anext);
    __builtin_amdgcn_s_barrier();
    asm volatile("s_waitcnt lgkmcnt(0)" ::: "memory");
    __builtin_amdgcn_sched_barrier(0);
    __builtin_amdgcn_s_setprio(1);
#pragma unroll
    for (int m = 0; m < 4; ++m)
#pragma unroll
      for (int n = 0; n < 2; ++n)
#pragma unroll
        for (int kk = 0; kk < 2; ++kk)
          acc[m][n] =
              __builtin_amdgcn_mfma_f32_16x16x32_bf16(a[m][kk], b01[n][kk], acc[m][n], 0, 0, 0);
    __builtin_amdgcn_s_setprio(0);
    __builtin_amdgcn_s_barrier();

    // ===== phase 2: read b23 ; stage A1(t+1) ; MFMA Q(mh0,n23) =====
#pragma unroll
    for (int n = 0; n < 2; ++n)
#pragma unroll
      for (int kk = 0; kk < 2; ++kk) {
        int row = brow0 + (2 + n) * 16 + l15;
        int col = (kk * 32 + g4 * 8) ^ ((row & 7) << 3);
        b23[n][kk] = *(const bf16x8*)&Bs[row * 64 + col];
      }
    if (t + 1 < NT) stage(buf ^ 1, 1, Anext + (size_t)128 * K_DIM);
    __builtin_amdgcn_s_barrier();
    asm volatile("s_waitcnt lgkmcnt(0)" ::: "memory");
    __builtin_amdgcn_sched_barrier(0);
    __builtin_amdgcn_s_setprio(1);
#pragma unroll
    for (int m = 0; m < 4; ++m)
#pragma unroll
      for (int n = 0; n < 2; ++n)
#pragma unroll
        for (int kk = 0; kk < 2; ++kk)
          acc[m][2 + n] = __builtin_amdgcn_mfma_f32_16x16x32_bf16(a[m][kk], b23[n][kk],
                                                                  acc[m][2 + n], 0, 0, 0);
    __builtin_amdgcn_s_setprio(0);
    __builtin_amdgcn_s_barrier();

    // ===== phase 3: read a(mh1) ; stage B0(t+2) ; MFMA Q(mh1,n01) =====
#pragma unroll
    for (int m = 0; m < 4; ++m)
#pragma unroll
      for (int kk = 0; kk < 2; ++kk) {
        int row = 64 + m * 16 + l15;
        int col = (kk * 32 + g4 * 8) ^ ((row & 7) << 3);
        a[m][kk] = *(const bf16x8*)&As[row * 64 + col];
      }
    if (t + 2 < NT) stage(buf, 2, Bnext2);
    __builtin_amdgcn_s_barrier();
    asm volatile("s_waitcnt lgkmcnt(0)" ::: "memory");
    __builtin_amdgcn_sched_barrier(0);
    __builtin_amdgcn_s_setprio(1);
#pragma unroll
    for (int m = 0; m < 4; ++m)
#pragma unroll
      for (int n = 0; n < 2; ++n)
#pragma unroll
        for (int kk = 0; kk < 2; ++kk)
          acc[4 + m][n] = __builtin_amdgcn_mfma_f32_16x16x32_bf16(a[m][kk], b01[n][kk],
                                                                  acc[4 + m][n], 0, 0, 0);
    __builtin_amdgcn_s_setprio(0);
    __builtin_amdgcn_s_barrier();

    // ===== phase 4: stage B1(t+2) ; MFMA Q(mh1,n23) ; counted vmcnt =====
    if (t + 2 < NT) stage(buf, 3, Bnext2 + (size_t)128 * K_DIM);
    __builtin_amdgcn_s_barrier();
    __builtin_amdgcn_s_setprio(1);
#pragma unroll
    for (int m = 0; m < 4; ++m)
#pragma unroll
      for (int n = 0; n < 2; ++n)
#pragma unroll
        for (int kk = 0; kk < 2; ++kk)
          acc[4 + m][2 + n] = __builtin_amdgcn_mfma_f32_16x16x32_bf16(a[m][kk], b23[n][kk],
                                                                      acc[4 + m][2 + n], 0, 0, 0);
    __builtin_amdgcn_s_setprio(0);
    // drain tile t+1's half-tiles; keep B(t+2) (4 loads) in flight
    if (t + 2 < NT)
      asm volatile("s_waitcnt vmcnt(4)" ::: "memory");
    else
      asm volatile("s_waitcnt vmcnt(0)" ::: "memory");
    __builtin_amdgcn_s_barrier();
  }

  // ---- epilogue: C/D layout col = lane&15, row = (lane>>4)*4 + reg ----
  const int crow0 = bm + wr * 128;
  const int ccol0 = bn + wc * 64;
#pragma unroll
  for (int m = 0; m < 8; ++m)
#pragma unroll
    for (int n = 0; n < 4; ++n)
#pragma unroll
      for (int j = 0; j < 4; ++j)
        C[(size_t)(crow0 + m * 16 + g4 * 4 + j) * N_DIM + ccol0 + n * 16 + l15] = acc[m][n][j];
}

// -------- naive fallback (only if workspace is too small) --------
__global__ void naive_bin_gemm(const float* __restrict__ X, const float* __restrict__ W,
                               float* __restrict__ C) {
  int j = blockIdx.x * blockDim.x + threadIdx.x;
  int i = blockIdx.y;
  if (j >= N_DIM) return;
  float s = 0.0f;
  for (int k = 0; k < K_DIM; ++k) {
    float xv = X[(size_t)i * K_DIM + k];
    float wv = W[(size_t)k * N_DIM + j];
    float sx = (float)((xv > 0.0f) - (xv < 0.0f));
    float sw = (float)((wv > 0.0f) - (wv < 0.0f));
    s += sx * sw;
  }
  C[(size_t)i * N_DIM + j] = s;
}

extern "C" void kernel_launch(void* const* d_in, const int* in_sizes, int n_in,
                              void* d_out, int out_size, void* d_ws, size_t ws_size,
                              hipStream_t stream) {
  const float* x = (const float*)d_in[0];  // [M][K]
  const float* w = (const float*)d_in[1];  // [K][N]
  float* out = (float*)d_out;              // [M][N]

  const size_t xb_bytes = (size_t)M_DIM * K_DIM * sizeof(u16);
  const size_t wt_bytes = (size_t)K_DIM * N_DIM * sizeof(u16);

  if (ws_size >= xb_bytes + wt_bytes) {
    u16* xb = (u16*)d_ws;
    u16* wt = (u16*)((char*)d_ws + xb_bytes);

    binarize_x_kernel<<<2048, 256, 0, stream>>>(x, xb, M_DIM * K_DIM / 4);
    binT_w_kernel<<<dim3(N_DIM / 64, K_DIM / 64), dim3(256), 0, stream>>>(w, wt);

    const int grid = (M_DIM / BM) * (N_DIM / BN);  // 32 * 16 = 512
    gemm_bin_8ph<<<grid, 512, 0, stream>>>(xb, wt, out);
  } else {
    naive_bin_gemm<<<dim3(N_DIM / 256, M_DIM), dim3(256), 0, stream>>>(x, w, out);
  }
}

// Round 3
// 178.390 us; speedup vs baseline: 2.1137x; 1.5122x over previous
//
#include <hip/hip_runtime.h>
#include <stdint.h>

#define M_DIM 8192
#define K_DIM 4096
#define N_DIM 4096

typedef signed char i8;
typedef unsigned char u8;
typedef int i32x4 __attribute__((ext_vector_type(4)));
typedef float float4v __attribute__((ext_vector_type(4)));
typedef u8 u8x4 __attribute__((ext_vector_type(4)));

// sign(v) as int8: +1 / -1 / 0
__device__ __forceinline__ i8 sign_i8(float v) {
  return (i8)((v > 0.0f) - (v < 0.0f));
}

// ---------------- binarize X: [M][K] f32 -> [M][K] i8(sign) ----------------
__global__ void binarize_x_kernel(const float* __restrict__ in, u8* __restrict__ out, int n4) {
  int i = blockIdx.x * blockDim.x + threadIdx.x;
  int stride = gridDim.x * blockDim.x;
  for (; i < n4; i += stride) {
    float4v v = ((const float4v*)in)[i];
    u8x4 o;
    o.x = (u8)sign_i8(v.x);
    o.y = (u8)sign_i8(v.y);
    o.z = (u8)sign_i8(v.z);
    o.w = (u8)sign_i8(v.w);
    ((u8x4*)out)[i] = o;
  }
}

// ------- binarize + transpose W: [K][N] f32 -> [N][K] i8(sign) -------------
__global__ void binT_w_kernel(const float* __restrict__ w, u8* __restrict__ wT) {
  __shared__ u8 tile[64][65];
  const int bn = blockIdx.x * 64;
  const int bk = blockIdx.y * 64;
  const int tid = threadIdx.x;

#pragma unroll
  for (int it = 0; it < 4; ++it) {
    int idx = tid + it * 256;
    int r = idx >> 4;             // k-local
    int c = (idx & 15) * 4;       // n-local
    float4v v = *(const float4v*)&w[(size_t)(bk + r) * N_DIM + bn + c];
    tile[c + 0][r] = (u8)sign_i8(v.x);
    tile[c + 1][r] = (u8)sign_i8(v.y);
    tile[c + 2][r] = (u8)sign_i8(v.z);
    tile[c + 3][r] = (u8)sign_i8(v.w);
  }
  __syncthreads();
#pragma unroll
  for (int it = 0; it < 4; ++it) {
    int idx = tid + it * 256;
    int rn = idx >> 4;            // n-local
    int ck = (idx & 15) * 4;      // k-local
    u8x4 o;
    o.x = tile[rn][ck + 0];
    o.y = tile[rn][ck + 1];
    o.z = tile[rn][ck + 2];
    o.w = tile[rn][ck + 3];
    *(u8x4*)&wT[(size_t)(bn + rn) * K_DIM + bk + ck] = o;
  }
}

// ------------------------------------------------------------------
// 8-phase 256x256 i8 GEMM: C[M][N] = A[M][K] * Bt[N][K]^T, i8 in, f32 out.
// mfma_i32_16x16x64_i8, BK=128 (rows are 128 B — byte-identical geometry to
// the validated bf16 BK=64 schedule). 8 waves (2M x 4N), double-buffered LDS,
// 4 phases/K-tile, T2 byte-XOR swizzle via pre-swizzled global source,
// counted vmcnt(4), setprio around MFMA clusters.
// ------------------------------------------------------------------
#define BM 256
#define BN 256
#define BK 128
#define NT (K_DIM / BK)   // 32

__device__ __forceinline__ void gload_lds16(const u8* g, u8* l) {
  __builtin_amdgcn_global_load_lds(
      (const __attribute__((address_space(1))) void*)g,
      (__attribute__((address_space(3))) void*)l, 16, 0, 0);
}

__global__ __launch_bounds__(512, 2) void gemm_bin_i8(const u8* __restrict__ A,
                                                      const u8* __restrict__ Bt,
                                                      float* __restrict__ C) {
  // slots: 0 = A rows[0,128), 1 = A rows[128,256), 2 = Bt[0,128), 3 = Bt[128,256)
  // each slot 128 rows x 128 B = 16 KiB; 2 bufs x 4 slots = 128 KiB.
  __shared__ u8 lds[2][4][128 * 128];

  const int tid = threadIdx.x;
  const int lane = tid & 63;
  const int wid = tid >> 6;  // 0..7
  const int wr = wid >> 2;   // 0..1 (M half)
  const int wc = wid & 3;    // 0..3 (N quarter)

  // XCD-aware swizzle, nwg = 512 (divisible by 8 -> bijective)
  const int b = blockIdx.x;
  const int sw = (b & 7) * (gridDim.x >> 3) + (b >> 3);
  const int tiles_n = N_DIM / BN;  // 16
  const int bm = (sw / tiles_n) * BM;
  const int bn = (sw % tiles_n) * BN;

  const int l15 = lane & 15;
  const int g4 = lane >> 4;
  const int srow = lane >> 3;                                 // 0..7
  const int swzb = (((lane & 7) ^ (lane >> 3)) & 7) << 4;     // pre-swizzled byte col
  // lane's swizzled byte col: ((lane&7)*16) ^ (srow<<4), srow = row&7 of its row
  const int swz_src = (((lane & 7) ^ srow) << 4);

  // stage one 128x128B half-tile (2 x global_load_lds per wave).
  auto stage = [&](int buf, int slot, const u8* gbase) {
#pragma unroll
    for (int i = 0; i < 2; ++i) {
      const u8* g = gbase + (size_t)(i * 64 + wid * 8 + srow) * K_DIM + swz_src;
      gload_lds16(g, &lds[buf][slot][(i * 64 + wid * 8) * 128]);
    }
  };

  i32x4 acc[8][4] = {};

  // ---- prologue: tile0 fully + B-halves of tile1 (6 half-tiles, 12 loads) ----
  {
    const u8* Abase = A + (size_t)bm * K_DIM;
    const u8* Bbase = Bt + (size_t)bn * K_DIM;
    stage(0, 0, Abase);
    stage(0, 1, Abase + (size_t)128 * K_DIM);
    stage(0, 2, Bbase);
    stage(0, 3, Bbase + (size_t)128 * K_DIM);
    stage(1, 2, Bbase + BK);
    stage(1, 3, Bbase + (size_t)128 * K_DIM + BK);
  }
  asm volatile("s_waitcnt vmcnt(4)" ::: "memory");  // tile0 ready, B(1) in flight
  __builtin_amdgcn_s_barrier();

  i32x4 a[4][2], b01[2][2], b23[2][2];

  for (int t = 0; t < NT; ++t) {
    const int buf = t & 1;
    const int kt = t * BK;
    const u8* As = &lds[buf][wr][0];
    const u8* Bs = &lds[buf][2 + (wc >> 1)][0];
    const int brow0 = (wc & 1) * 64;
    const u8* Anext = A + (size_t)bm * K_DIM + kt + BK;        // tile t+1
    const u8* Bnext2 = Bt + (size_t)bn * K_DIM + kt + 2 * BK;  // tile t+2

    // ===== phase 1: read a(mh0) + b01 ; stage A0(t+1) ; MFMA Q(mh0,n01) =====
#pragma unroll
    for (int m = 0; m < 4; ++m)
#pragma unroll
      for (int kk = 0; kk < 2; ++kk) {
        int row = m * 16 + l15;
        int col = (kk * 64 + g4 * 16) ^ ((row & 7) << 4);
        a[m][kk] = *(const i32x4*)&As[row * 128 + col];
      }
#pragma unroll
    for (int n = 0; n < 2; ++n)
#pragma unroll
      for (int kk = 0; kk < 2; ++kk) {
        int row = brow0 + n * 16 + l15;
        int col = (kk * 64 + g4 * 16) ^ ((row & 7) << 4);
        b01[n][kk] = *(const i32x4*)&Bs[row * 128 + col];
      }
    if (t + 1 < NT) stage(buf ^ 1, 0, Anext);
    __builtin_amdgcn_s_barrier();
    asm volatile("s_waitcnt lgkmcnt(0)" ::: "memory");
    __builtin_amdgcn_sched_barrier(0);
    __builtin_amdgcn_s_setprio(1);
#pragma unroll
    for (int m = 0; m < 4; ++m)
#pragma unroll
      for (int n = 0; n < 2; ++n)
#pragma unroll
        for (int kk = 0; kk < 2; ++kk)
          acc[m][n] =
              __builtin_amdgcn_mfma_i32_16x16x64_i8(a[m][kk], b01[n][kk], acc[m][n], 0, 0, 0);
    __builtin_amdgcn_s_setprio(0);
    __builtin_amdgcn_s_barrier();

    // ===== phase 2: read b23 ; stage A1(t+1) ; MFMA Q(mh0,n23) =====
#pragma unroll
    for (int n = 0; n < 2; ++n)
#pragma unroll
      for (int kk = 0; kk < 2; ++kk) {
        int row = brow0 + (2 + n) * 16 + l15;
        int col = (kk * 64 + g4 * 16) ^ ((row & 7) << 4);
        b23[n][kk] = *(const i32x4*)&Bs[row * 128 + col];
      }
    if (t + 1 < NT) stage(buf ^ 1, 1, Anext + (size_t)128 * K_DIM);
    __builtin_amdgcn_s_barrier();
    asm volatile("s_waitcnt lgkmcnt(0)" ::: "memory");
    __builtin_amdgcn_sched_barrier(0);
    __builtin_amdgcn_s_setprio(1);
#pragma unroll
    for (int m = 0; m < 4; ++m)
#pragma unroll
      for (int n = 0; n < 2; ++n)
#pragma unroll
        for (int kk = 0; kk < 2; ++kk)
          acc[m][2 + n] = __builtin_amdgcn_mfma_i32_16x16x64_i8(a[m][kk], b23[n][kk],
                                                                acc[m][2 + n], 0, 0, 0);
    __builtin_amdgcn_s_setprio(0);
    __builtin_amdgcn_s_barrier();

    // ===== phase 3: read a(mh1) ; stage B0(t+2) ; MFMA Q(mh1,n01) =====
#pragma unroll
    for (int m = 0; m < 4; ++m)
#pragma unroll
      for (int kk = 0; kk < 2; ++kk) {
        int row = 64 + m * 16 + l15;
        int col = (kk * 64 + g4 * 16) ^ ((row & 7) << 4);
        a[m][kk] = *(const i32x4*)&As[row * 128 + col];
      }
    if (t + 2 < NT) stage(buf, 2, Bnext2);
    __builtin_amdgcn_s_barrier();
    asm volatile("s_waitcnt lgkmcnt(0)" ::: "memory");
    __builtin_amdgcn_sched_barrier(0);
    __builtin_amdgcn_s_setprio(1);
#pragma unroll
    for (int m = 0; m < 4; ++m)
#pragma unroll
      for (int n = 0; n < 2; ++n)
#pragma unroll
        for (int kk = 0; kk < 2; ++kk)
          acc[4 + m][n] = __builtin_amdgcn_mfma_i32_16x16x64_i8(a[m][kk], b01[n][kk],
                                                                acc[4 + m][n], 0, 0, 0);
    __builtin_amdgcn_s_setprio(0);
    __builtin_amdgcn_s_barrier();

    // ===== phase 4: stage B1(t+2) ; MFMA Q(mh1,n23) ; counted vmcnt =====
    if (t + 2 < NT) stage(buf, 3, Bnext2 + (size_t)128 * K_DIM);
    __builtin_amdgcn_s_barrier();
    __builtin_amdgcn_s_setprio(1);
#pragma unroll
    for (int m = 0; m < 4; ++m)
#pragma unroll
      for (int n = 0; n < 2; ++n)
#pragma unroll
        for (int kk = 0; kk < 2; ++kk)
          acc[4 + m][2 + n] = __builtin_amdgcn_mfma_i32_16x16x64_i8(a[m][kk], b23[n][kk],
                                                                    acc[4 + m][2 + n], 0, 0, 0);
    __builtin_amdgcn_s_setprio(0);
    // drain tile t+1's half-tiles; keep B(t+2) (4 loads) in flight
    if (t + 2 < NT)
      asm volatile("s_waitcnt vmcnt(4)" ::: "memory");
    else
      asm volatile("s_waitcnt vmcnt(0)" ::: "memory");
    __builtin_amdgcn_s_barrier();
  }

  // ---- epilogue: C/D layout col = lane&15, row = (lane>>4)*4 + reg ----
  const int crow0 = bm + wr * 128;
  const int ccol0 = bn + wc * 64;
#pragma unroll
  for (int m = 0; m < 8; ++m)
#pragma unroll
    for (int n = 0; n < 4; ++n)
#pragma unroll
      for (int j = 0; j < 4; ++j)
        C[(size_t)(crow0 + m * 16 + g4 * 4 + j) * N_DIM + ccol0 + n * 16 + l15] =
            (float)acc[m][n][j];
}

// -------- naive fallback (only if workspace is too small) --------
__global__ void naive_bin_gemm(const float* __restrict__ X, const float* __restrict__ W,
                               float* __restrict__ C) {
  int j = blockIdx.x * blockDim.x + threadIdx.x;
  int i = blockIdx.y;
  if (j >= N_DIM) return;
  float s = 0.0f;
  for (int k = 0; k < K_DIM; ++k) {
    float xv = X[(size_t)i * K_DIM + k];
    float wv = W[(size_t)k * N_DIM + j];
    float sx = (float)((xv > 0.0f) - (xv < 0.0f));
    float sw = (float)((wv > 0.0f) - (wv < 0.0f));
    s += sx * sw;
  }
  C[(size_t)i * N_DIM + j] = s;
}

extern "C" void kernel_launch(void* const* d_in, const int* in_sizes, int n_in,
                              void* d_out, int out_size, void* d_ws, size_t ws_size,
                              hipStream_t stream) {
  const float* x = (const float*)d_in[0];  // [M][K]
  const float* w = (const float*)d_in[1];  // [K][N]
  float* out = (float*)d_out;              // [M][N]

  const size_t xb_bytes = (size_t)M_DIM * K_DIM;  // 33.5 MB (i8)
  const size_t wt_bytes = (size_t)K_DIM * N_DIM;  // 16.8 MB (i8)

  if (ws_size >= xb_bytes + wt_bytes) {
    u8* xb = (u8*)d_ws;
    u8* wt = (u8*)((char*)d_ws + xb_bytes);

    binarize_x_kernel<<<2048, 256, 0, stream>>>(x, xb, M_DIM * K_DIM / 4);
    binT_w_kernel<<<dim3(N_DIM / 64, K_DIM / 64), dim3(256), 0, stream>>>(w, wt);

    const int grid = (M_DIM / BM) * (N_DIM / BN);  // 32 * 16 = 512
    gemm_bin_i8<<<grid, 512, 0, stream>>>(xb, wt, out);
  } else {
    naive_bin_gemm<<<dim3(N_DIM / 256, M_DIM), dim3(256), 0, stream>>>(x, w, out);
  }
}

// Round 4
// 129.186 us; speedup vs baseline: 2.9187x; 1.3809x over previous
//
#include <hip/hip_runtime.h>
#include <stdint.h>

#define M_DIM 8192
#define K_DIM 4096
#define N_DIM 4096
#define KB (K_DIM / 2)  // bytes per packed-fp4 row: 2048

typedef unsigned char u8;
typedef unsigned int u32;
typedef int i32x4 __attribute__((ext_vector_type(4)));
typedef int i32x8 __attribute__((ext_vector_type(8)));
typedef float f32x4 __attribute__((ext_vector_type(4)));
typedef float float4v __attribute__((ext_vector_type(4)));
typedef u32 u32x2 __attribute__((ext_vector_type(2)));

// sign(v) as fp4 e2m1 code: +1 -> 0x2, -1 -> 0xA, 0 -> 0x0
__device__ __forceinline__ u32 sign_fp4(float v) {
  return v > 0.0f ? 0x2u : (v < 0.0f ? 0xAu : 0x0u);
}

// -------- binarize X: [M][K] f32 -> [M][K/2] packed fp4 (k-major nibbles) ----
__global__ void binarize_x_kernel(const float* __restrict__ in, u32* __restrict__ out, int n8) {
  int i = blockIdx.x * blockDim.x + threadIdx.x;
  int stride = gridDim.x * blockDim.x;
  for (; i < n8; i += stride) {
    float4v v0 = ((const float4v*)in)[2 * i];
    float4v v1 = ((const float4v*)in)[2 * i + 1];
    u32 w = sign_fp4(v0.x) | (sign_fp4(v0.y) << 4) | (sign_fp4(v0.z) << 8) |
            (sign_fp4(v0.w) << 12) | (sign_fp4(v1.x) << 16) | (sign_fp4(v1.y) << 20) |
            (sign_fp4(v1.z) << 24) | (sign_fp4(v1.w) << 28);
    out[i] = w;
  }
}

// ---- binarize + transpose W: [K][N] f32 -> [N][K/2] packed fp4 -------------
__global__ void binT_w_kernel(const float* __restrict__ w, u8* __restrict__ wT) {
  __shared__ u8 tile[64][65];  // fp4 code per (n, k)
  const int bn = blockIdx.x * 64;
  const int bk = blockIdx.y * 64;
  const int tid = threadIdx.x;

#pragma unroll
  for (int it = 0; it < 4; ++it) {
    int idx = tid + it * 256;
    int r = idx >> 4;        // k-local
    int c = (idx & 15) * 4;  // n-local
    float4v v = *(const float4v*)&w[(size_t)(bk + r) * N_DIM + bn + c];
    tile[c + 0][r] = (u8)sign_fp4(v.x);
    tile[c + 1][r] = (u8)sign_fp4(v.y);
    tile[c + 2][r] = (u8)sign_fp4(v.z);
    tile[c + 3][r] = (u8)sign_fp4(v.w);
  }
  __syncthreads();
  // pack: each thread emits 8 bytes (16 k-codes) of one n-row
  const int rn = tid >> 2;         // n-local 0..63
  const int cb = (tid & 3) * 8;    // byte offset 0..24 within the 32-B chunk
  u32x2 o;
  u32 lo = 0, hi = 0;
#pragma unroll
  for (int j = 0; j < 4; ++j) {
    lo |= (u32)(tile[rn][cb * 2 + 2 * j] | (tile[rn][cb * 2 + 2 * j + 1] << 4)) << (8 * j);
    hi |= (u32)(tile[rn][cb * 2 + 8 + 2 * j] | (tile[rn][cb * 2 + 9 + 2 * j] << 4)) << (8 * j);
  }
  o.x = lo;
  o.y = hi;
  *(u32x2*)&wT[(size_t)(bn + rn) * KB + (bk >> 1) + cb] = o;
}

// ------------------------------------------------------------------
// 8-phase 256x256 fp4 GEMM: C[M][N] = A[M][K] * Bt[N][K]^T, fp4 in, f32 out.
// mfma_scale_f32_16x16x128_f8f6f4 (fp4/fp4, scale=1.0). K-tile = 256 elems =
// 128 B rows — byte-identical geometry to the validated i8 BK=128 schedule.
// 8 waves (2M x 4N), double-buffered LDS, 4 phases/K-tile, T2 byte-XOR
// swizzle via pre-swizzled global source, counted vmcnt(4), setprio.
// ------------------------------------------------------------------
#define BM 256
#define BN 256
#define BKB 128            // bytes of K per tile (= 256 fp4 elems)
#define NT (K_DIM / 256)   // 16

__device__ __forceinline__ void gload_lds16(const u8* g, u8* l) {
  __builtin_amdgcn_global_load_lds(
      (const __attribute__((address_space(1))) void*)g,
      (__attribute__((address_space(3))) void*)l, 16, 0, 0);
}

__device__ __forceinline__ i32x8 pad8(i32x4 v) {
  return __builtin_shufflevector(v, v, 0, 1, 2, 3, 0, 1, 2, 3);
}

// fp4 x fp4, per-lane e8m0 scale byte 0x7F (=1.0), opsel byte 0
__device__ __forceinline__ f32x4 mfma_fp4(i32x4 a, i32x4 b, f32x4 c) {
  return __builtin_amdgcn_mfma_scale_f32_16x16x128_f8f6f4(pad8(a), pad8(b), c, 4, 4, 0, 0x7F, 0,
                                                          0x7F);
}

__global__ __launch_bounds__(512, 2) void gemm_bin_fp4(const u8* __restrict__ A,
                                                       const u8* __restrict__ Bt,
                                                       float* __restrict__ C) {
  // slots: 0 = A rows[0,128), 1 = A rows[128,256), 2 = Bt[0,128), 3 = Bt[128,256)
  // each slot 128 rows x 128 B = 16 KiB; 2 bufs x 4 slots = 128 KiB.
  __shared__ u8 lds[2][4][128 * 128];

  const int tid = threadIdx.x;
  const int lane = tid & 63;
  const int wid = tid >> 6;  // 0..7
  const int wr = wid >> 2;   // 0..1 (M half)
  const int wc = wid & 3;    // 0..3 (N quarter)

  // XCD-aware swizzle, nwg = 512 (divisible by 8 -> bijective)
  const int b = blockIdx.x;
  const int sw = (b & 7) * (gridDim.x >> 3) + (b >> 3);
  const int tiles_n = N_DIM / BN;  // 16
  const int bm = (sw / tiles_n) * BM;
  const int bn = (sw % tiles_n) * BN;

  const int l15 = lane & 15;
  const int g4 = lane >> 4;
  const int srow = lane >> 3;                              // 0..7
  const int swz_src = (((lane & 7) ^ srow) << 4);          // pre-swizzled byte col

  // stage one 128-row x 128-B half-tile (2 x global_load_lds per wave).
  auto stage = [&](int buf, int slot, const u8* gbase) {
#pragma unroll
    for (int i = 0; i < 2; ++i) {
      const u8* g = gbase + (size_t)(i * 64 + wid * 8 + srow) * KB + swz_src;
      gload_lds16(g, &lds[buf][slot][(i * 64 + wid * 8) * 128]);
    }
  };

  f32x4 acc[8][4] = {};

  // ---- prologue: tile0 fully + B-halves of tile1 (6 half-tiles, 12 loads) ----
  {
    const u8* Abase = A + (size_t)bm * KB;
    const u8* Bbase = Bt + (size_t)bn * KB;
    stage(0, 0, Abase);
    stage(0, 1, Abase + (size_t)128 * KB);
    stage(0, 2, Bbase);
    stage(0, 3, Bbase + (size_t)128 * KB);
    stage(1, 2, Bbase + BKB);
    stage(1, 3, Bbase + (size_t)128 * KB + BKB);
  }
  asm volatile("s_waitcnt vmcnt(4)" ::: "memory");  // tile0 ready, B(1) in flight
  __builtin_amdgcn_s_barrier();

  i32x4 a[4][2], b01[2][2], b23[2][2];

  for (int t = 0; t < NT; ++t) {
    const int buf = t & 1;
    const u8* As = &lds[buf][wr][0];
    const u8* Bs = &lds[buf][2 + (wc >> 1)][0];
    const int brow0 = (wc & 1) * 64;
    const u8* Anext = A + (size_t)bm * KB + (t + 1) * BKB;         // tile t+1
    const u8* Bnext2 = Bt + (size_t)bn * KB + (t + 2) * BKB;       // tile t+2

    // ===== phase 1: read a(mh0) + b01 ; stage A0(t+1) ; MFMA Q(mh0,n01) =====
#pragma unroll
    for (int m = 0; m < 4; ++m)
#pragma unroll
      for (int kk = 0; kk < 2; ++kk) {
        int row = m * 16 + l15;
        int col = (kk * 64 + g4 * 16) ^ ((row & 7) << 4);
        a[m][kk] = *(const i32x4*)&As[row * 128 + col];
      }
#pragma unroll
    for (int n = 0; n < 2; ++n)
#pragma unroll
      for (int kk = 0; kk < 2; ++kk) {
        int row = brow0 + n * 16 + l15;
        int col = (kk * 64 + g4 * 16) ^ ((row & 7) << 4);
        b01[n][kk] = *(const i32x4*)&Bs[row * 128 + col];
      }
    if (t + 1 < NT) stage(buf ^ 1, 0, Anext);
    __builtin_amdgcn_s_barrier();
    asm volatile("s_waitcnt lgkmcnt(0)" ::: "memory");
    __builtin_amdgcn_sched_barrier(0);
    __builtin_amdgcn_s_setprio(1);
#pragma unroll
    for (int kk = 0; kk < 2; ++kk)
#pragma unroll
      for (int m = 0; m < 4; ++m)
#pragma unroll
        for (int n = 0; n < 2; ++n)
          acc[m][n] = mfma_fp4(a[m][kk], b01[n][kk], acc[m][n]);
    __builtin_amdgcn_s_setprio(0);
    __builtin_amdgcn_s_barrier();

    // ===== phase 2: read b23 ; stage A1(t+1) ; MFMA Q(mh0,n23) =====
#pragma unroll
    for (int n = 0; n < 2; ++n)
#pragma unroll
      for (int kk = 0; kk < 2; ++kk) {
        int row = brow0 + (2 + n) * 16 + l15;
        int col = (kk * 64 + g4 * 16) ^ ((row & 7) << 4);
        b23[n][kk] = *(const i32x4*)&Bs[row * 128 + col];
      }
    if (t + 1 < NT) stage(buf ^ 1, 1, Anext + (size_t)128 * KB);
    __builtin_amdgcn_s_barrier();
    asm volatile("s_waitcnt lgkmcnt(0)" ::: "memory");
    __builtin_amdgcn_sched_barrier(0);
    __builtin_amdgcn_s_setprio(1);
#pragma unroll
    for (int kk = 0; kk < 2; ++kk)
#pragma unroll
      for (int m = 0; m < 4; ++m)
#pragma unroll
        for (int n = 0; n < 2; ++n)
          acc[m][2 + n] = mfma_fp4(a[m][kk], b23[n][kk], acc[m][2 + n]);
    __builtin_amdgcn_s_setprio(0);
    __builtin_amdgcn_s_barrier();

    // ===== phase 3: read a(mh1) ; stage B0(t+2) ; MFMA Q(mh1,n01) =====
#pragma unroll
    for (int m = 0; m < 4; ++m)
#pragma unroll
      for (int kk = 0; kk < 2; ++kk) {
        int row = 64 + m * 16 + l15;
        int col = (kk * 64 + g4 * 16) ^ ((row & 7) << 4);
        a[m][kk] = *(const i32x4*)&As[row * 128 + col];
      }
    if (t + 2 < NT) stage(buf, 2, Bnext2);
    __builtin_amdgcn_s_barrier();
    asm volatile("s_waitcnt lgkmcnt(0)" ::: "memory");
    __builtin_amdgcn_sched_barrier(0);
    __builtin_amdgcn_s_setprio(1);
#pragma unroll
    for (int kk = 0; kk < 2; ++kk)
#pragma unroll
      for (int m = 0; m < 4; ++m)
#pragma unroll
        for (int n = 0; n < 2; ++n)
          acc[4 + m][n] = mfma_fp4(a[m][kk], b01[n][kk], acc[4 + m][n]);
    __builtin_amdgcn_s_setprio(0);
    __builtin_amdgcn_s_barrier();

    // ===== phase 4: stage B1(t+2) ; MFMA Q(mh1,n23) ; counted vmcnt =====
    if (t + 2 < NT) stage(buf, 3, Bnext2 + (size_t)128 * KB);
    __builtin_amdgcn_s_barrier();
    __builtin_amdgcn_s_setprio(1);
#pragma unroll
    for (int kk = 0; kk < 2; ++kk)
#pragma unroll
      for (int m = 0; m < 4; ++m)
#pragma unroll
        for (int n = 0; n < 2; ++n)
          acc[4 + m][2 + n] = mfma_fp4(a[m][kk], b23[n][kk], acc[4 + m][2 + n]);
    __builtin_amdgcn_s_setprio(0);
    // drain tile t+1's half-tiles; keep B(t+2) (4 loads) in flight
    if (t + 2 < NT)
      asm volatile("s_waitcnt vmcnt(4)" ::: "memory");
    else
      asm volatile("s_waitcnt vmcnt(0)" ::: "memory");
    __builtin_amdgcn_s_barrier();
  }

  // ---- epilogue: C/D layout col = lane&15, row = (lane>>4)*4 + reg ----
  const int crow0 = bm + wr * 128;
  const int ccol0 = bn + wc * 64;
#pragma unroll
  for (int m = 0; m < 8; ++m)
#pragma unroll
    for (int n = 0; n < 4; ++n)
#pragma unroll
      for (int j = 0; j < 4; ++j)
        C[(size_t)(crow0 + m * 16 + g4 * 4 + j) * N_DIM + ccol0 + n * 16 + l15] = acc[m][n][j];
}

// -------- naive fallback (only if workspace is too small) --------
__global__ void naive_bin_gemm(const float* __restrict__ X, const float* __restrict__ W,
                               float* __restrict__ C) {
  int j = blockIdx.x * blockDim.x + threadIdx.x;
  int i = blockIdx.y;
  if (j >= N_DIM) return;
  float s = 0.0f;
  for (int k = 0; k < K_DIM; ++k) {
    float xv = X[(size_t)i * K_DIM + k];
    float wv = W[(size_t)k * N_DIM + j];
    float sx = (float)((xv > 0.0f) - (xv < 0.0f));
    float sw = (float)((wv > 0.0f) - (wv < 0.0f));
    s += sx * sw;
  }
  C[(size_t)i * N_DIM + j] = s;
}

extern "C" void kernel_launch(void* const* d_in, const int* in_sizes, int n_in,
                              void* d_out, int out_size, void* d_ws, size_t ws_size,
                              hipStream_t stream) {
  const float* x = (const float*)d_in[0];  // [M][K]
  const float* w = (const float*)d_in[1];  // [K][N]
  float* out = (float*)d_out;              // [M][N]

  const size_t xb_bytes = (size_t)M_DIM * KB;  // 16.8 MB
  const size_t wt_bytes = (size_t)N_DIM * KB;  // 8.4 MB

  if (ws_size >= xb_bytes + wt_bytes) {
    u8* xb = (u8*)d_ws;
    u8* wt = (u8*)((char*)d_ws + xb_bytes);

    binarize_x_kernel<<<2048, 256, 0, stream>>>(x, (u32*)xb, M_DIM * K_DIM / 8);
    binT_w_kernel<<<dim3(N_DIM / 64, K_DIM / 64), dim3(256), 0, stream>>>(w, wt);

    const int grid = (M_DIM / BM) * (N_DIM / BN);  // 32 * 16 = 512
    gemm_bin_fp4<<<grid, 512, 0, stream>>>(xb, wt, out);
  } else {
    naive_bin_gemm<<<dim3(N_DIM / 256, M_DIM), dim3(256), 0, stream>>>(x, w, out);
  }
}